// Round 8
// baseline (400.956 us; speedup 1.0000x reference)
//
#include <hip/hip_runtime.h>
#include <stdint.h>
#include <math.h>

#define WAVE 64
#define WPB 4              // independent waves per block
#define APW 2              // atoms per wave
#define APB (WPB*APW)      // 8 atoms per block
#define NMAX 2048
#define SEL0 46
#define SEL1 92
#define ASEL0 16
#define ASEL1 32
#define NNB 138            // SEL0+SEL1
#define NANG 48
#define DDIM 282
#define HID 64
#define FEPS 1e-16f
#define CAP 128

typedef unsigned long long u64;

__device__ __forceinline__ float mimg(float dx, float box, float ibox) {
    return dx - box * rintf(dx * ibox);   // jnp.round = rintf
}
__device__ __forceinline__ float decode_box(const void* boxp) {
    int ib = ((const int*)boxp)[0];
    return (ib > 0 && ib < 1000000) ? (float)ib : ((const float*)boxp)[0];
}
__device__ __forceinline__ u64 casx_(u64 v, int stride, bool asc, bool keep_lo) {
    u64 o = __shfl_xor(v, stride, 64);
    return (asc == keep_lo) ? (v < o ? v : o) : (v > o ? v : o);
}
// wave-local LDS drain (waves never cross-sync except the two block barriers)
#define WSYNC() __asm__ __volatile__("s_waitcnt lgkmcnt(0)" ::: "memory")

// W0T[m*DDIM+d] = W0[d*HID+m];  W1T[m*HID+l] = W1[l*HID+m]
__global__ __launch_bounds__(256)
void tr_kernel(const float* __restrict__ W0a, const float* __restrict__ W0b,
               const float* __restrict__ W1a, const float* __restrict__ W1b,
               float* __restrict__ W0Ta, float* __restrict__ W0Tb,
               float* __restrict__ W1Ta, float* __restrict__ W1Tb)
{
    int idx = blockIdx.x * 256 + threadIdx.x;
    if (idx < DDIM * HID) {
        int d = idx / HID, m = idx % HID;
        W0Ta[m * DDIM + d] = W0a[idx];
        W0Tb[m * DDIM + d] = W0b[idx];
    }
    if (idx < HID * HID) {
        int l = idx / HID, m = idx % HID;
        W1Ta[m * HID + l] = W1a[idx];
        W1Tb[m * HID + l] = W1b[idx];
    }
}

__global__ __launch_bounds__(256)
void md_kernel(const float* __restrict__ xyz, const int* __restrict__ types,
               const void* __restrict__ boxp,
               const float* __restrict__ W0a, const float* __restrict__ B0a,
               const float* __restrict__ W1a, const float* __restrict__ B1a,
               const float* __restrict__ W2a, const float* __restrict__ B2a,
               const float* __restrict__ W0b, const float* __restrict__ B0b,
               const float* __restrict__ W1b, const float* __restrict__ B1b,
               const float* __restrict__ W2b, const float* __restrict__ B2b,
               const float* __restrict__ W0Ta, const float* __restrict__ W0Tb,
               const float* __restrict__ W1Ta, const float* __restrict__ W1Tb,
               float* __restrict__ out, int B, int N)
{
    const int tid = threadIdx.x;
    const int wv = tid >> 6, lane = tid & 63;
    const int blk = blockIdx.x;
    const int atom_base = blk * APB;
    const int BN = B * N;
    const int b = (atom_base < BN) ? (atom_base / N) : 0;

    __shared__ float4 P[NMAX];                 // x,y,z,type (bits)
    __shared__ u64   A0s[WPB][CAP], A1s[WPB][CAP];
    __shared__ float snd_[WPB][NNB];
    __shared__ int   sni_[WPB][NNB];
    __shared__ float sdesc_[WPB][DDIM];
    __shared__ float sg_[WPB][DDIM];
    __shared__ float sAm_[WPB][9];
    __shared__ float sh1_[WPB][HID], sdh2_[WPB][HID], sdh1_[WPB][HID];
    __shared__ float sG_[WPB][9];
    __shared__ float sFi_[WPB][3];
    __shared__ int   cnt_[WPB][2];
    __shared__ float sE;

    u64*   wA0 = A0s[wv];  u64*   wA1 = A1s[wv];
    float* wsnd = snd_[wv]; int*  wsni = sni_[wv];
    float* wdesc = sdesc_[wv]; float* wg = sg_[wv];
    float* wAm = sAm_[wv];
    float* wh1 = sh1_[wv]; float* wdh2 = sdh2_[wv]; float* wdh1 = sdh1_[wv];
    float* wG = sG_[wv];   float* wFi = sFi_[wv];
    int*   wcnt = cnt_[wv];

    const float box = decode_box(boxp);
    const float ibox = 1.0f / box;
    const float* Xg = xyz + (size_t)b * N * 3;
    const int*   Tg = types + (size_t)b * N;

    // ---- stage positions+types into LDS (once per block) ----
    if (tid == 0) sE = 0.0f;
    for (int j = tid; j < N && j < NMAX; j += 256) {
        P[j] = make_float4(Xg[3*j+0], Xg[3*j+1], Xg[3*j+2],
                           __int_as_float(Tg[j]));
    }
    __syncthreads();

    float* Fout = out + B;
    float esum = 0.0f;   // lane0-held wave energy

    const float vol = box * box * box;
    const float c43pi = 4.18879020f;
    const int NIT = (N + WAVE - 1) / WAVE;     // pair iterations (<=32)

    for (int a = 0; a < APW; ++a) {
        const int atom = atom_base + wv * APW + a;
        if (atom >= BN) continue;              // uniform per wave
        const int i = atom - b * N;
        const float4 pi = P[i];
        const float xi = pi.x, yi = pi.y, zi = pi.z;
        const int ti = __float_as_int(pi.w);

        // ---- 16-bit keys from LDS, 2 per u32 reg ----
        uint32_t kp[16];
        int t1cnt = 0;
        for (int it = 0; it < 32; ++it) {
            uint32_t k16 = 0xFFFFu;
            int j = it * WAVE + lane;
            if (it < NIT && j < N && j != i) {
                float4 p = P[j];
                float dx = mimg(xi - p.x, box, ibox);
                float dy = mimg(yi - p.y, box, ibox);
                float dz = mimg(zi - p.z, box, ibox);
                float d = sqrtf(dx*dx + dy*dy + dz*dz);
                int tj = __float_as_int(p.w);
                k16 = (__float_as_uint(d) >> 16) | (tj ? 0x8000u : 0u);
                t1cnt += (tj != 0);
            }
            if (it & 1) kp[it >> 1] |= (k16 << 16);
            else        kp[it >> 1]  = k16;
        }
        #pragma unroll
        for (int o = 1; o < 64; o <<= 1) t1cnt += __shfl_xor(t1cnt, o, 64);
        const int tot1 = t1cnt;
        const int tot0 = (N - 1) - tot1;
        const int need0 = min(SEL0, tot0);
        const int need1 = min(SEL1, tot1);

        // ---- integer bisection on 15-bit key space ----
        float R0 = cbrtf(0.5f * (need0 + CAP) * vol / (c43pi * fmaxf((float)tot0, 1.0f)));
        float R1 = cbrtf(0.5f * (need1 + CAP) * vol / (c43pi * fmaxf((float)tot1, 1.0f)));
        uint32_t thr0 = (__float_as_uint(R0) >> 16) & 0x7FFFu;
        uint32_t thr1 = (__float_as_uint(R1) >> 16) & 0x7FFFu;
        uint32_t lo0 = 0, hi0 = 0x7FFFu, lo1 = 0, hi1 = 0x7FFFu;
        for (int itb = 0; itb < 18; ++itb) {
            uint32_t c0 = 0, c1 = 0;
            #pragma unroll
            for (int q = 0; q < 16; ++q) {
                uint32_t ka = kp[q] & 0xFFFFu, kb = kp[q] >> 16;
                c0 += (ka < 0x8000u && ka < thr0);
                c0 += (kb < 0x8000u && kb < thr0);
                c1 += (ka >= 0x8000u && (ka & 0x7FFFu) < thr1);
                c1 += (kb >= 0x8000u && (kb & 0x7FFFu) < thr1);
            }
            uint32_t packed = c0 | (c1 << 16);
            #pragma unroll
            for (int o = 1; o < 64; o <<= 1) packed += __shfl_xor(packed, o, 64);
            int cc0 = (int)(packed & 0xFFFFu), cc1 = (int)(packed >> 16);
            bool d0 = (cc0 >= need0 && cc0 <= CAP);
            bool d1 = (cc1 >= need1 && cc1 <= CAP);
            if (d0 && d1) break;
            if (!d0) { if (cc0 < need0) lo0 = thr0; else hi0 = thr0; thr0 = (lo0 + hi0) >> 1; }
            if (!d1) { if (cc1 < need1) lo1 = thr1; else hi1 = thr1; thr1 = (lo1 + hi1) >> 1; }
        }

        // ---- compact candidates (exact distances from LDS) ----
        if (lane == 0) { wcnt[0] = 0; wcnt[1] = 0; }
        WSYNC();
        for (int it = 0; it < NIT; ++it) {
            uint32_t k = (it & 1) ? (kp[it >> 1] >> 16) : (kp[it >> 1] & 0xFFFFu);
            bool is1 = (k >= 0x8000u);
            uint32_t kd = k & 0x7FFFu;
            bool hit = (k != 0xFFFFu) && (is1 ? (kd < thr1) : (kd < thr0));
            if (hit) {
                int j = it * WAVE + lane;
                float4 p = P[j];
                float dx = mimg(xi - p.x, box, ibox);
                float dy = mimg(yi - p.y, box, ibox);
                float dz = mimg(zi - p.z, box, ibox);
                float d = sqrtf(dx*dx + dy*dy + dz*dz);
                u64 key = ((u64)__float_as_uint(d) << 32) | (uint32_t)j;
                if (is1) { int pos = atomicAdd(&wcnt[1], 1); if (pos < CAP) wA1[pos] = key; }
                else     { int pos = atomicAdd(&wcnt[0], 1); if (pos < CAP) wA0[pos] = key; }
            }
        }
        WSYNC();
        const int c0 = min(wcnt[0], CAP);
        const int c1 = min(wcnt[1], CAP);
        if (lane      >= c0) wA0[lane]      = ~0ull;
        if (lane + 64 >= c0) wA0[lane + 64] = ~0ull;
        if (lane      >= c1) wA1[lane]      = ~0ull;
        if (lane + 64 >= c1) wA1[lane + 64] = ~0ull;
        if (lane < 9) wG[lane] = 0.0f;
        if (lane < 3) wFi[lane] = 0.0f;
        WSYNC();

        // ---- dual interleaved register bitonic sort (128 each) ----
        {
            u64 a0 = wA0[lane], a1 = wA0[lane + 64];
            u64 b0 = wA1[lane], b1 = wA1[lane + 64];
            #pragma unroll
            for (int size = 2; size <= 128; size <<= 1) {
                #pragma unroll
                for (int stride = 64; stride > 0; stride >>= 1) {
                    if (stride >= size) continue;
                    if (stride == 64) {
                        u64 mn = a0 < a1 ? a0 : a1;
                        u64 mx = a0 < a1 ? a1 : a0;
                        a0 = mn; a1 = mx;
                        mn = b0 < b1 ? b0 : b1;
                        mx = b0 < b1 ? b1 : b0;
                        b0 = mn; b1 = mx;
                    } else {
                        bool keep_lo = (lane & stride) == 0;
                        bool asc0 = ((lane & size) == 0);
                        bool asc1 = (((lane + 64) & size) == 0);
                        a0 = casx_(a0, stride, asc0, keep_lo);
                        a1 = casx_(a1, stride, asc1, keep_lo);
                        b0 = casx_(b0, stride, asc0, keep_lo);
                        b1 = casx_(b1, stride, asc1, keep_lo);
                    }
                }
            }
            wA0[lane] = a0; wA0[lane + 64] = a1;
            wA1[lane] = b0; wA1[lane + 64] = b1;
        }
        WSYNC();

        // ---- neighbor tables + radial features ----
        for (int s = lane; s < NNB; s += WAVE) {
            u64 k; bool valid;
            if (s < SEL0) { valid = (s < c0); k = wA0[s]; }
            else          { int t2 = s - SEL0; valid = (t2 < c1); k = wA1[t2]; }
            float d = 1e30f; int j = -1;
            if (valid) {
                d = __uint_as_float((uint32_t)(k >> 32));
                j = (int)(uint32_t)(k & 0xFFFFFFFFull);
            }
            wsnd[s] = d; wsni[s] = j;
            wdesc[s] = 1.0f / (d + FEPS);
        }
        WSYNC();

        // ---- local frame (lane 0; state stays in registers) ----
        float f_ld0=1.0f, f_ld1=1.0f; int f_j0=-1, f_j1=-1;
        float r0x=0,r0y=0,r0z=0, r1x=0,r1y=0,r1z=0;
        float u0x=0,u0y=0,u0z=0, u1x=0,u1y=0,u1z=0;
        float f_s=0, f_n2=1, f_n3=1;
        float e2x=0,e2y=0,e2z=0, e3x=0,e3y=0,e3z=0;
        if (lane == 0) {
            float da0 = wsnd[0],  db0 = wsnd[SEL0];
            float da1 = wsnd[1],  db1 = wsnd[SEL0+1];
            int   ja0 = wsni[0],  jb0 = wsni[SEL0];
            int   ja1 = wsni[1],  jb1 = wsni[SEL0+1];
            f_ld0 = (db0 < da0) ? db0 : da0;  f_j0 = (db0 < da0) ? jb0 : ja0;
            f_ld1 = (db1 < da1) ? db1 : da1;  f_j1 = (db1 < da1) ? jb1 : ja1;
            if (f_j0 < 0) f_j0 = i;
            if (f_j1 < 0) f_j1 = i;
            float4 p0 = P[f_j0], p1 = P[f_j1];
            u0x = mimg(xi - p0.x, box, ibox);
            u0y = mimg(yi - p0.y, box, ibox);
            u0z = mimg(zi - p0.z, box, ibox);
            u1x = mimg(xi - p1.x, box, ibox);
            u1y = mimg(yi - p1.y, box, ibox);
            u1z = mimg(zi - p1.z, box, ibox);
            float id0 = 1.0f/(f_ld0 + FEPS), id1 = 1.0f/(f_ld1 + FEPS);
            r0x = u0x*id0; r0y = u0y*id0; r0z = u0z*id0;
            r1x = u1x*id1; r1y = u1y*id1; r1z = u1z*id1;
            f_s = r0x*r1x + r0y*r1y + r0z*r1z;
            float v2x = r1x - f_s*r0x, v2y = r1y - f_s*r0y, v2z = r1z - f_s*r0z;
            f_n2 = sqrtf(v2x*v2x + v2y*v2y + v2z*v2z);
            e2x = v2x/f_n2; e2y = v2y/f_n2; e2z = v2z/f_n2;
            float cx = r0y*r1z - r0z*r1y;
            float cy = r0z*r1x - r0x*r1z;
            float cz = r0x*r1y - r0y*r1x;
            f_n3 = sqrtf(cx*cx + cy*cy + cz*cz);
            e3x = cx/f_n3; e3y = cy/f_n3; e3z = cz/f_n3;
            wAm[0]=r0x; wAm[1]=r0y; wAm[2]=r0z;
            wAm[3]=e2x; wAm[4]=e2y; wAm[5]=e2z;
            wAm[6]=e3x; wAm[7]=e3y; wAm[8]=e3z;
        }
        WSYNC();

        // ---- angular features ----
        if (lane < NANG) {
            int slot = (lane < ASEL0) ? lane : SEL0 + (lane - ASEL0);
            float d = wsnd[slot]; int j = wsni[slot];
            float dx = 0, dy = 0, dz = 0;
            if (j >= 0) {
                float4 p = P[j];
                dx = mimg(xi - p.x, box, ibox);
                dy = mimg(yi - p.y, box, ibox);
                dz = mimg(zi - p.z, box, ibox);
            }
            float de = d + FEPS;
            float q = 1.0f/(de*de);
            float wx = wAm[0]*dx + wAm[1]*dy + wAm[2]*dz;
            float wy = wAm[3]*dx + wAm[4]*dy + wAm[5]*dz;
            float wz = wAm[6]*dx + wAm[7]*dy + wAm[8]*dz;
            wdesc[NNB + 3*lane + 0] = wx*q;
            wdesc[NNB + 3*lane + 1] = wy*q;
            wdesc[NNB + 3*lane + 2] = wz*q;
        }
        WSYNC();

        // ---- MLP forward + backward (lane == hidden index) ----
        const float* W0 = ti ? W0b : W0a;  const float* B0 = ti ? B0b : B0a;
        const float* W1 = ti ? W1b : W1a;  const float* B1 = ti ? B1b : B1a;
        const float* W2 = ti ? W2b : W2a;  const float* B2 = ti ? B2b : B2a;
        const float* W0T = ti ? W0Tb : W0Ta;
        const float* W1T = ti ? W1Tb : W1Ta;

        float acc0 = B0[lane];
        #pragma unroll 4
        for (int d = 0; d < DDIM; ++d) acc0 = fmaf(wdesc[d], W0[d*HID + lane], acc0);
        float h1 = tanhf(acc0);
        wh1[lane] = h1;
        WSYNC();

        float acc1 = B1[lane];
        #pragma unroll 8
        for (int m = 0; m < HID; ++m) acc1 = fmaf(wh1[m], W1[m*HID + lane], acc1);
        float h2 = tanhf(acc1);
        float w2 = W2[lane];
        float part = h2 * w2;
        #pragma unroll
        for (int o = 32; o > 0; o >>= 1) part += __shfl_down(part, o, 64);
        if (lane == 0) esum += part + B2[0];
        wdh2[lane] = (1.0f - h2*h2) * w2;
        WSYNC();

        float acc2 = 0.0f;
        if (W1T) {
            #pragma unroll 8
            for (int m = 0; m < HID; ++m) acc2 = fmaf(W1T[m*HID + lane], wdh2[m], acc2);
        } else {
            for (int m = 0; m < HID; ++m) acc2 = fmaf(W1[lane*HID + m], wdh2[m], acc2);
        }
        wdh1[lane] = (1.0f - h1*h1) * acc2;
        WSYNC();

        if (W0T) {
            float g0=0, g1=0, g2=0, g3=0, g4=0;
            #pragma unroll 4
            for (int m = 0; m < HID; ++m) {
                float dh = wdh1[m];
                const float* row = W0T + m*DDIM;
                g0 = fmaf(row[lane      ], dh, g0);
                g1 = fmaf(row[lane +  64], dh, g1);
                g2 = fmaf(row[lane + 128], dh, g2);
                g3 = fmaf(row[lane + 192], dh, g3);
                if (lane + 256 < DDIM) g4 = fmaf(row[lane + 256], dh, g4);
            }
            wg[lane      ] = g0;
            wg[lane +  64] = g1;
            wg[lane + 128] = g2;
            wg[lane + 192] = g3;
            if (lane + 256 < DDIM) wg[lane + 256] = g4;
        } else {
            for (int d = lane; d < DDIM; d += WAVE) {
                float acc = 0.0f;
                for (int m = 0; m < HID; ++m) acc = fmaf(W0[d*HID + m], wdh1[m], acc);
                wg[d] = acc;
            }
        }
        WSYNC();

        // ---- gradient scatter (direct atomics) ----
        for (int s = lane; s < NNB; s += WAVE) {
            float d = wsnd[s]; int j = wsni[s];
            if (j >= 0) {
                float4 p = P[j];
                float dx = mimg(xi - p.x, box, ibox);
                float dy = mimg(yi - p.y, box, ibox);
                float dz = mimg(zi - p.z, box, ibox);
                float gr = wg[s];
                float de = d + FEPS;
                float coef = -gr / (d * de * de);
                float gx = coef*dx, gy = coef*dy, gz = coef*dz;
                int aa = -1;
                if (s < ASEL0) aa = s;
                else if (s >= SEL0 && s < SEL0 + ASEL1) aa = ASEL0 + (s - SEL0);
                if (aa >= 0) {
                    float q = 1.0f/(de*de);
                    float gax = wg[NNB+3*aa+0], gay = wg[NNB+3*aa+1], gaz = wg[NNB+3*aa+2];
                    float wx = wAm[0]*dx + wAm[1]*dy + wAm[2]*dz;
                    float wy = wAm[3]*dx + wAm[4]*dy + wAm[5]*dz;
                    float wz = wAm[6]*dx + wAm[7]*dy + wAm[8]*dz;
                    float tx = wAm[0]*gax + wAm[3]*gay + wAm[6]*gaz;
                    float ty = wAm[1]*gax + wAm[4]*gay + wAm[7]*gaz;
                    float tz = wAm[2]*gax + wAm[5]*gay + wAm[8]*gaz;
                    float gw = gax*wx + gay*wy + gaz*wz;
                    float c2 = -2.0f * gw * q / (de * d);
                    gx += q*tx + c2*dx;
                    gy += q*ty + c2*dy;
                    gz += q*tz + c2*dz;
                    atomicAdd(&wG[0], gax*dx*q); atomicAdd(&wG[1], gax*dy*q); atomicAdd(&wG[2], gax*dz*q);
                    atomicAdd(&wG[3], gay*dx*q); atomicAdd(&wG[4], gay*dy*q); atomicAdd(&wG[5], gay*dz*q);
                    atomicAdd(&wG[6], gaz*dx*q); atomicAdd(&wG[7], gaz*dy*q); atomicAdd(&wG[8], gaz*dz*q);
                }
                float* Fj = Fout + 3*((size_t)b*N + j);
                atomicAdd(&Fj[0], gx); atomicAdd(&Fj[1], gy); atomicAdd(&Fj[2], gz);
                atomicAdd(&wFi[0], -gx); atomicAdd(&wFi[1], -gy); atomicAdd(&wFi[2], -gz);
            }
        }
        WSYNC();

        // ---- frame backward (lane 0) ----
        if (lane == 0 && f_j0 >= 0) {
            float g0x=wG[0], g0y=wG[1], g0z=wG[2];
            float g2x=wG[3], g2y=wG[4], g2z=wG[5];
            float g3x=wG[6], g3y=wG[7], g3z=wG[8];
            float d3 = g3x*e3x + g3y*e3y + g3z*e3z;
            float in3 = 1.0f/f_n3;
            float dcx = (g3x - d3*e3x)*in3;
            float dcy = (g3y - d3*e3y)*in3;
            float dcz = (g3z - d3*e3z)*in3;
            float gr0x = r1y*dcz - r1z*dcy;
            float gr0y = r1z*dcx - r1x*dcz;
            float gr0z = r1x*dcy - r1y*dcx;
            float gr1x = dcy*r0z - dcz*r0y;
            float gr1y = dcz*r0x - dcx*r0z;
            float gr1z = dcx*r0y - dcy*r0x;
            float d2 = g2x*e2x + g2y*e2y + g2z*e2z;
            float in2 = 1.0f/f_n2;
            float dvx = (g2x - d2*e2x)*in2;
            float dvy = (g2y - d2*e2y)*in2;
            float dvz = (g2z - d2*e2z)*in2;
            gr1x += dvx; gr1y += dvy; gr1z += dvz;
            gr0x -= f_s*dvx; gr0y -= f_s*dvy; gr0z -= f_s*dvz;
            float dss = -(dvx*r0x + dvy*r0y + dvz*r0z);
            gr0x += dss*r1x; gr0y += dss*r1y; gr0z += dss*r1z;
            gr1x += dss*r0x; gr1y += dss*r0y; gr1z += dss*r0z;
            gr0x += g0x; gr0y += g0y; gr0z += g0z;
            float de0 = f_ld0 + FEPS;
            float dot0 = gr0x*u0x + gr0y*u0y + gr0z*u0z;
            float k0 = dot0 / (f_ld0 * de0 * de0);
            float gu0x = gr0x/de0 - k0*u0x;
            float gu0y = gr0y/de0 - k0*u0y;
            float gu0z = gr0z/de0 - k0*u0z;
            float de1 = f_ld1 + FEPS;
            float dot1 = gr1x*u1x + gr1y*u1y + gr1z*u1z;
            float k1 = dot1 / (f_ld1 * de1 * de1);
            float gu1x = gr1x/de1 - k1*u1x;
            float gu1y = gr1y/de1 - k1*u1y;
            float gu1z = gr1z/de1 - k1*u1z;
            float* Fj0 = Fout + 3*((size_t)b*N + f_j0);
            atomicAdd(&Fj0[0], gu0x); atomicAdd(&Fj0[1], gu0y); atomicAdd(&Fj0[2], gu0z);
            float* Fj1 = Fout + 3*((size_t)b*N + f_j1);
            atomicAdd(&Fj1[0], gu1x); atomicAdd(&Fj1[1], gu1y); atomicAdd(&Fj1[2], gu1z);
            wFi[0] -= gu0x + gu1x;
            wFi[1] -= gu0y + gu1y;
            wFi[2] -= gu0z + gu1z;
        }
        WSYNC();
        if (lane < 3) {
            atomicAdd(&Fout[3*((size_t)b*N + i) + lane], wFi[lane]);
        }
        WSYNC();
    }

    // ---- hierarchical energy: wave partial -> LDS -> one global atomic ----
    if (lane == 0) atomicAdd(&sE, esum);
    __syncthreads();
    if (tid == 0) atomicAdd(&out[b], sE);
}

extern "C" void kernel_launch(void* const* d_in, const int* in_sizes, int n_in,
                              void* d_out, int out_size, void* d_ws, size_t ws_size,
                              hipStream_t stream) {
    const float* xyz  = (const float*)d_in[0];
    const int*   types = (const int*)d_in[1];
    const void*  boxp = d_in[2];
    int BN = in_sizes[1];              // B*N
    int B = out_size - 3*BN;           // out = energy(B) + forces(3BN)
    if (B < 1) B = 1;
    int N = BN / B;

    size_t trBytes = (2*(size_t)(DDIM*HID) + 2*(size_t)(HID*HID)) * sizeof(float);
    float *W0Ta = nullptr, *W0Tb = nullptr, *W1Ta = nullptr, *W1Tb = nullptr;
    if (ws_size >= trBytes) {
        float* base = (float*)d_ws;
        W0Ta = base;
        W0Tb = W0Ta + DDIM*HID;
        W1Ta = W0Tb + DDIM*HID;
        W1Tb = W1Ta + HID*HID;
    }

    hipMemsetAsync(d_out, 0, (size_t)out_size * sizeof(float), stream);

    if (W0Ta) {
        int nb = (DDIM * HID + 255) / 256;
        tr_kernel<<<dim3(nb), dim3(256), 0, stream>>>(
            (const float*)d_in[3], (const float*)d_in[9],
            (const float*)d_in[5], (const float*)d_in[11],
            W0Ta, W0Tb, W1Ta, W1Tb);
    }

    int nbA = (BN + APB - 1) / APB;
    md_kernel<<<dim3(nbA), dim3(256), 0, stream>>>(
        xyz, types, boxp,
        (const float*)d_in[3],  (const float*)d_in[4],
        (const float*)d_in[5],  (const float*)d_in[6],
        (const float*)d_in[7],  (const float*)d_in[8],
        (const float*)d_in[9],  (const float*)d_in[10],
        (const float*)d_in[11], (const float*)d_in[12],
        (const float*)d_in[13], (const float*)d_in[14],
        W0Ta, W0Tb, W1Ta, W1Tb,
        (float*)d_out, B, N);
}

// Round 9
// 344.319 us; speedup vs baseline: 1.1645x; 1.1645x over previous
//
#include <hip/hip_runtime.h>
#include <stdint.h>
#include <math.h>

#define WAVE 64
#define WPB 4              // independent waves per block, 1 atom each
#define SEL0 46
#define SEL1 92
#define ASEL0 16
#define ASEL1 32
#define NNB 138            // SEL0+SEL1
#define NANG 48
#define DDIM 282
#define HID 64
#define FEPS 1e-16f
#define CAP 128
#define NBIN 512
#define NRECROW 140        // grec row stride (<=139 used)

typedef unsigned long long u64;
typedef unsigned short u16;

__device__ __forceinline__ float mimg(float dx, float box, float ibox) {
    return dx - box * rintf(dx * ibox);   // jnp.round = rintf
}
__device__ __forceinline__ float decode_box(const void* boxp) {
    int ib = ((const int*)boxp)[0];
    return (ib > 0 && ib < 1000000) ? (float)ib : ((const float*)boxp)[0];
}
__device__ __forceinline__ void cas_(u64& a, u64& b, bool asc) {
    u64 mn = a < b ? a : b;
    u64 mx = a < b ? b : a;
    a = asc ? mn : mx;
    b = asc ? mx : mn;
}
__device__ __forceinline__ u64 casx_(u64 v, int stride, bool asc, bool keep_lo) {
    u64 o = __shfl_xor(v, stride, 64);
    return (asc == keep_lo) ? (v < o ? v : o) : (v > o ? v : o);
}
#define WSYNC() __asm__ __volatile__("s_waitcnt lgkmcnt(0)" ::: "memory")

// builds X4 (xyz+type) and transposed weights
__global__ __launch_bounds__(256)
void prep_kernel(const float* __restrict__ xyz, const int* __restrict__ types,
                 float4* __restrict__ X4, int BN,
                 const float* __restrict__ W0a, const float* __restrict__ W0b,
                 const float* __restrict__ W1a, const float* __restrict__ W1b,
                 float* __restrict__ W0Ta, float* __restrict__ W0Tb,
                 float* __restrict__ W1Ta, float* __restrict__ W1Tb, int haveW)
{
    int idx = blockIdx.x * 256 + threadIdx.x;
    if (idx < BN) {
        X4[idx] = make_float4(xyz[3*idx+0], xyz[3*idx+1], xyz[3*idx+2],
                              __int_as_float(types[idx]));
    }
    if (haveW) {
        if (idx < DDIM * HID) {
            int d = idx / HID, m = idx % HID;
            W0Ta[m * DDIM + d] = W0a[idx];
            W0Tb[m * DDIM + d] = W0b[idx];
        }
        if (idx < HID * HID) {
            int l = idx / HID, m = idx % HID;
            W1Ta[m * HID + l] = W1a[idx];
            W1Tb[m * HID + l] = W1b[idx];
        }
    }
}

__global__ __launch_bounds__(256)
void md_kernel(const float4* __restrict__ X4, const void* __restrict__ boxp,
               const float* __restrict__ W0a, const float* __restrict__ B0a,
               const float* __restrict__ W1a, const float* __restrict__ B1a,
               const float* __restrict__ W2a, const float* __restrict__ B2a,
               const float* __restrict__ W0b, const float* __restrict__ B0b,
               const float* __restrict__ W1b, const float* __restrict__ B1b,
               const float* __restrict__ W2b, const float* __restrict__ B2b,
               const float* __restrict__ W0Ta, const float* __restrict__ W0Tb,
               const float* __restrict__ W1Ta, const float* __restrict__ W1Tb,
               float* __restrict__ out, float* __restrict__ grec,
               u64* __restrict__ bmT, u16* __restrict__ pcntT,
               int use_gather, int B, int N)
{
    const int wv = threadIdx.x >> 6;
    const int lane = threadIdx.x & 63;
    const int atom = blockIdx.x * WPB + wv;
    const int BNtot = B * N;
    if (atom >= BNtot) return;
    const int b = atom / N;
    const int i = atom - b * N;

    // 2KB/wave overlay scratch: hist(512 u32) -> A0/A1(2x128 u64) -> wg(3x140 f32)+bitmap(64 u32)
    __shared__ u64   scr_[WPB][256];
    __shared__ float snd_[WPB][NNB];
    __shared__ int   sni_[WPB][NNB];
    __shared__ float desc_[WPB][DDIM];
    __shared__ float g_[WPB][DDIM];
    __shared__ float h1_[WPB][HID], dh2_[WPB][HID], dh1_[WPB][HID];
    __shared__ float Am_[WPB][9];
    __shared__ float G_[WPB][9];
    __shared__ float Fi_[WPB][3];
    __shared__ int   cnt_[WPB][4];

    u64*   scr  = scr_[wv];
    float* wsnd = snd_[wv];  int* wsni = sni_[wv];
    float* wdesc = desc_[wv]; float* wg = g_[wv];
    float* wh1 = h1_[wv]; float* wdh2 = dh2_[wv]; float* wdh1 = dh1_[wv];
    float* wAm = Am_[wv]; float* wG = G_[wv]; float* wFi = Fi_[wv];
    int*   icnt = cnt_[wv];

    const float box = decode_box(boxp);
    const float ibox = 1.0f / box;
    const int bofs = b * N;
    const float4 pi = X4[bofs + i];
    const float xi = pi.x, yi = pi.y, zi = pi.z;
    const int ti = __float_as_int(pi.w);
    const int NIT = (N + WAVE - 1) / WAVE;
    const float binscale = (float)NBIN / (box * 0.8660254f + 1.0f);

    // ---- pass 1: histogram over linear-d bins, both types packed in u32 ----
    int* hist = (int*)scr;
    for (int k = lane; k < NBIN; k += WAVE) hist[k] = 0;
    WSYNC();
    for (int it = 0; it < NIT; ++it) {
        int j = it * WAVE + lane;
        if (j < N && j != i) {
            float4 p = X4[bofs + j];
            float dx = mimg(xi - p.x, box, ibox);
            float dy = mimg(yi - p.y, box, ibox);
            float dz = mimg(zi - p.z, box, ibox);
            float d = sqrtf(dx*dx + dy*dy + dz*dz);
            int bin = min(NBIN - 1, (int)(d * binscale));
            atomicAdd(&hist[bin], __float_as_int(p.w) ? 0x10000 : 1);
        }
    }
    WSYNC();

    // ---- scan 512 bins (8/lane), find per-type boundary bin ----
    int thr0b, thr1b;
    {
        int loc[8]; int ssum = 0;
        #pragma unroll
        for (int r = 0; r < 8; ++r) { loc[r] = hist[lane*8 + r]; ssum += loc[r]; }
        int cum = ssum;
        for (int o = 1; o < 64; o <<= 1) {
            int v = __shfl_up(cum, o, 64);
            if (lane >= o) cum += v;
        }
        int tot = __shfl(cum, 63, 64);
        int tot0 = tot & 0xFFFF, tot1 = (tot >> 16) & 0xFFFF;
        int need0 = min(SEL0, tot0), need1 = min(SEL1, tot1);
        if (lane == 0) { icnt[0] = -1; icnt[1] = -1; }
        WSYNC();
        int c0 = cum & 0xFFFF,          s0 = ssum & 0xFFFF;
        int c1 = (cum >> 16) & 0xFFFF,  s1 = (ssum >> 16) & 0xFFFF;
        u64 m0 = __ballot(need0 > 0 && c0 >= need0);
        u64 m1 = __ballot(need1 > 0 && c1 >= need1);
        int L0 = m0 ? (__ffsll(m0) - 1) : -1;
        int L1 = m1 ? (__ffsll(m1) - 1) : -1;
        if (lane == L0) {
            int c = c0 - s0;
            for (int r = 0; r < 8; ++r) { c += loc[r] & 0xFFFF; if (c >= need0) { icnt[0] = lane*8 + r; break; } }
        }
        if (lane == L1) {
            int c = c1 - s1;
            for (int r = 0; r < 8; ++r) { c += (loc[r] >> 16) & 0xFFFF; if (c >= need1) { icnt[1] = lane*8 + r; break; } }
        }
        WSYNC();
        thr0b = icnt[0]; thr1b = icnt[1];
    }

    // ---- pass 2: compact candidates with exact fp32-d keys ----
    u64* A0 = scr;        // overlay (hist dead)
    u64* A1 = scr + CAP;
    if (lane == 0) { icnt[2] = 0; icnt[3] = 0; }
    WSYNC();
    for (int it = 0; it < NIT; ++it) {
        int j = it * WAVE + lane;
        if (j < N && j != i) {
            float4 p = X4[bofs + j];
            float dx = mimg(xi - p.x, box, ibox);
            float dy = mimg(yi - p.y, box, ibox);
            float dz = mimg(zi - p.z, box, ibox);
            float d = sqrtf(dx*dx + dy*dy + dz*dz);
            int bin = min(NBIN - 1, (int)(d * binscale));
            int tj = __float_as_int(p.w);
            if (bin <= (tj ? thr1b : thr0b)) {
                u64 key = ((u64)__float_as_uint(d) << 32) | (uint32_t)j;
                int pos = atomicAdd(&icnt[2 + (tj ? 1 : 0)], 1);
                if (pos < CAP) (tj ? A1 : A0)[pos] = key;
            }
        }
    }
    WSYNC();
    const int c0 = min(icnt[2], CAP);
    const int c1 = min(icnt[3], CAP);
    if (lane      >= c0) A0[lane]      = ~0ull;
    if (lane + 64 >= c0) A0[lane + 64] = ~0ull;
    if (lane      >= c1) A1[lane]      = ~0ull;
    if (lane + 64 >= c1) A1[lane + 64] = ~0ull;
    if (lane < 9) wG[lane] = 0.0f;
    if (lane < 3) wFi[lane] = 0.0f;
    WSYNC();

    // ---- dual register bitonic sort (rolled) ----
    {
        u64 a0 = A0[lane], a1 = A0[lane + 64];
        u64 b0 = A1[lane], b1 = A1[lane + 64];
        #pragma unroll 1
        for (int size = 2; size <= 128; size <<= 1) {
            #pragma unroll 1
            for (int stride = size >> 1; stride > 0; stride >>= 1) {
                if (stride == 64) {
                    cas_(a0, a1, true);
                    cas_(b0, b1, true);
                } else {
                    bool keep_lo = (lane & stride) == 0;
                    bool asc0 = ((lane & size) == 0);
                    bool asc1 = (((lane + 64) & size) == 0);
                    a0 = casx_(a0, stride, asc0, keep_lo);
                    a1 = casx_(a1, stride, asc1, keep_lo);
                    b0 = casx_(b0, stride, asc0, keep_lo);
                    b1 = casx_(b1, stride, asc1, keep_lo);
                }
            }
        }
        A0[lane] = a0; A0[lane + 64] = a1;
        A1[lane] = b0; A1[lane + 64] = b1;
    }
    WSYNC();

    // ---- neighbor tables + radial features ----
    for (int s = lane; s < NNB; s += WAVE) {
        u64 k; bool valid;
        if (s < SEL0) { valid = (s < c0); k = A0[s]; }
        else          { int t2 = s - SEL0; valid = (t2 < c1); k = A1[t2]; }
        float d = 1e30f; int j = -1;
        if (valid) {
            d = __uint_as_float((uint32_t)(k >> 32));
            j = (int)(uint32_t)(k & 0xFFFFFFFFull);
        }
        wsnd[s] = d; wsni[s] = j;
        wdesc[s] = 1.0f / (d + FEPS);
    }
    WSYNC();

    // ---- local frame (lane 0) ----
    float f_ld0=1.0f, f_ld1=1.0f; int f_j0=-1, f_j1=-1, f_s0=0, f_s1=1;
    float r0x=0,r0y=0,r0z=0, r1x=0,r1y=0,r1z=0;
    float u0x=0,u0y=0,u0z=0, u1x=0,u1y=0,u1z=0;
    float f_s=0, f_n2=1, f_n3=1;
    float e2x=0,e2y=0,e2z=0, e3x=0,e3y=0,e3z=0;
    if (lane == 0) {
        float da0 = wsnd[0],  db0 = wsnd[SEL0];
        float da1 = wsnd[1],  db1 = wsnd[SEL0+1];
        int   ja0 = wsni[0],  jb0 = wsni[SEL0];
        int   ja1 = wsni[1],  jb1 = wsni[SEL0+1];
        bool p0 = (db0 < da0), p1 = (db1 < da1);
        f_ld0 = p0 ? db0 : da0;  f_j0 = p0 ? jb0 : ja0;  f_s0 = p0 ? SEL0 : 0;
        f_ld1 = p1 ? db1 : da1;  f_j1 = p1 ? jb1 : ja1;  f_s1 = p1 ? SEL0+1 : 1;
        if (f_j0 < 0) f_j0 = i;
        if (f_j1 < 0) f_j1 = i;
        float4 q0 = X4[bofs + f_j0], q1 = X4[bofs + f_j1];
        u0x = mimg(xi - q0.x, box, ibox);
        u0y = mimg(yi - q0.y, box, ibox);
        u0z = mimg(zi - q0.z, box, ibox);
        u1x = mimg(xi - q1.x, box, ibox);
        u1y = mimg(yi - q1.y, box, ibox);
        u1z = mimg(zi - q1.z, box, ibox);
        float id0 = 1.0f/(f_ld0 + FEPS), id1 = 1.0f/(f_ld1 + FEPS);
        r0x = u0x*id0; r0y = u0y*id0; r0z = u0z*id0;
        r1x = u1x*id1; r1y = u1y*id1; r1z = u1z*id1;
        f_s = r0x*r1x + r0y*r1y + r0z*r1z;
        float v2x = r1x - f_s*r0x, v2y = r1y - f_s*r0y, v2z = r1z - f_s*r0z;
        f_n2 = sqrtf(v2x*v2x + v2y*v2y + v2z*v2z);
        e2x = v2x/f_n2; e2y = v2y/f_n2; e2z = v2z/f_n2;
        float cx = r0y*r1z - r0z*r1y;
        float cy = r0z*r1x - r0x*r1z;
        float cz = r0x*r1y - r0y*r1x;
        f_n3 = sqrtf(cx*cx + cy*cy + cz*cz);
        e3x = cx/f_n3; e3y = cy/f_n3; e3z = cz/f_n3;
        wAm[0]=r0x; wAm[1]=r0y; wAm[2]=r0z;
        wAm[3]=e2x; wAm[4]=e2y; wAm[5]=e2z;
        wAm[6]=e3x; wAm[7]=e3y; wAm[8]=e3z;
    }
    WSYNC();

    // ---- angular features ----
    if (lane < NANG) {
        int slot = (lane < ASEL0) ? lane : SEL0 + (lane - ASEL0);
        float d = wsnd[slot]; int j = wsni[slot];
        float dx = 0, dy = 0, dz = 0;
        if (j >= 0) {
            float4 p = X4[bofs + j];
            dx = mimg(xi - p.x, box, ibox);
            dy = mimg(yi - p.y, box, ibox);
            dz = mimg(zi - p.z, box, ibox);
        }
        float de = d + FEPS;
        float q = 1.0f/(de*de);
        float wx = wAm[0]*dx + wAm[1]*dy + wAm[2]*dz;
        float wy = wAm[3]*dx + wAm[4]*dy + wAm[5]*dz;
        float wz = wAm[6]*dx + wAm[7]*dy + wAm[8]*dz;
        wdesc[NNB + 3*lane + 0] = wx*q;
        wdesc[NNB + 3*lane + 1] = wy*q;
        wdesc[NNB + 3*lane + 2] = wz*q;
    }
    WSYNC();

    // ---- MLP forward + backward (lane == hidden index) ----
    const float* W0 = ti ? W0b : W0a;  const float* B0 = ti ? B0b : B0a;
    const float* W1 = ti ? W1b : W1a;  const float* B1 = ti ? B1b : B1a;
    const float* W2 = ti ? W2b : W2a;  const float* B2 = ti ? B2b : B2a;
    const float* W0T = ti ? W0Tb : W0Ta;
    const float* W1T = ti ? W1Tb : W1Ta;

    float acc0 = B0[lane];
    #pragma unroll 4
    for (int d = 0; d < DDIM; ++d) acc0 = fmaf(wdesc[d], W0[d*HID + lane], acc0);
    float h1 = tanhf(acc0);
    wh1[lane] = h1;
    WSYNC();

    float acc1 = B1[lane];
    #pragma unroll 8
    for (int m = 0; m < HID; ++m) acc1 = fmaf(wh1[m], W1[m*HID + lane], acc1);
    float h2 = tanhf(acc1);
    float w2 = W2[lane];
    float part = h2 * w2;
    for (int o = 32; o > 0; o >>= 1) part += __shfl_down(part, o, 64);
    float esum = part + B2[0];          // lane0 meaningful
    wdh2[lane] = (1.0f - h2*h2) * w2;
    WSYNC();

    float acc2 = 0.0f;
    if (W1T) {
        #pragma unroll 8
        for (int m = 0; m < HID; ++m) acc2 = fmaf(W1T[m*HID + lane], wdh2[m], acc2);
    } else {
        for (int m = 0; m < HID; ++m) acc2 = fmaf(W1[lane*HID + m], wdh2[m], acc2);
    }
    wdh1[lane] = (1.0f - h1*h1) * acc2;
    WSYNC();

    if (W0T) {
        float g0=0, g1=0, g2=0, g3=0, g4=0;
        #pragma unroll 4
        for (int m = 0; m < HID; ++m) {
            float dh = wdh1[m];
            const float* row = W0T + m*DDIM;
            g0 = fmaf(row[lane      ], dh, g0);
            g1 = fmaf(row[lane +  64], dh, g1);
            g2 = fmaf(row[lane + 128], dh, g2);
            g3 = fmaf(row[lane + 192], dh, g3);
            if (lane + 256 < DDIM) g4 = fmaf(row[lane + 256], dh, g4);
        }
        wg[lane      ] = g0;
        wg[lane +  64] = g1;
        wg[lane + 128] = g2;
        wg[lane + 192] = g3;
        if (lane + 256 < DDIM) wg[lane + 256] = g4;
    } else {
        for (int d = lane; d < DDIM; d += WAVE) {
            float acc = 0.0f;
            for (int m = 0; m < HID; ++m) acc = fmaf(W0[d*HID + m], wdh1[m], acc);
            wg[d] = acc;
        }
    }
    WSYNC();

    // ---- per-slot gradients -> LDS records (overlay: A0/A1 dead) ----
    float* wgx = (float*)scr;
    float* wgy = wgx + NRECROW;
    float* wgz = wgy + NRECROW;
    uint32_t* wb = (uint32_t*)(scr + 210);   // 64 u32 bitmap words
    wb[lane] = 0;                             // lanes 0..63 clear all 64 words
    WSYNC();

    for (int s = lane; s < NNB; s += WAVE) {
        float gx = 0, gy = 0, gz = 0;
        float d = wsnd[s]; int j = wsni[s];
        if (j >= 0) {
            float4 p = X4[bofs + j];
            float dx = mimg(xi - p.x, box, ibox);
            float dy = mimg(yi - p.y, box, ibox);
            float dz = mimg(zi - p.z, box, ibox);
            float gr = wg[s];
            float de = d + FEPS;
            float coef = -gr / (d * de * de);
            gx = coef*dx; gy = coef*dy; gz = coef*dz;
            int aa = -1;
            if (s < ASEL0) aa = s;
            else if (s >= SEL0 && s < SEL0 + ASEL1) aa = ASEL0 + (s - SEL0);
            if (aa >= 0) {
                float q = 1.0f/(de*de);
                float gax = wg[NNB+3*aa+0], gay = wg[NNB+3*aa+1], gaz = wg[NNB+3*aa+2];
                float wx = wAm[0]*dx + wAm[1]*dy + wAm[2]*dz;
                float wy = wAm[3]*dx + wAm[4]*dy + wAm[5]*dz;
                float wz = wAm[6]*dx + wAm[7]*dy + wAm[8]*dz;
                float tx = wAm[0]*gax + wAm[3]*gay + wAm[6]*gaz;
                float ty = wAm[1]*gax + wAm[4]*gay + wAm[7]*gaz;
                float tz = wAm[2]*gax + wAm[5]*gay + wAm[8]*gaz;
                float gw = gax*wx + gay*wy + gaz*wz;
                float c2 = -2.0f * gw * q / (de * d);
                gx += q*tx + c2*dx;
                gy += q*ty + c2*dy;
                gz += q*tz + c2*dz;
                atomicAdd(&wG[0], gax*dx*q); atomicAdd(&wG[1], gax*dy*q); atomicAdd(&wG[2], gax*dz*q);
                atomicAdd(&wG[3], gay*dx*q); atomicAdd(&wG[4], gay*dy*q); atomicAdd(&wG[5], gay*dz*q);
                atomicAdd(&wG[6], gaz*dx*q); atomicAdd(&wG[7], gaz*dy*q); atomicAdd(&wG[8], gaz*dz*q);
            }
            atomicAdd(&wFi[0], -gx); atomicAdd(&wFi[1], -gy); atomicAdd(&wFi[2], -gz);
        }
        wgx[s] = gx; wgy[s] = gy; wgz[s] = gz;
    }
    WSYNC();

    // ---- frame backward (lane 0) -> fold into slots + self record ----
    if (lane == 0) {
        float g0x=wG[0], g0y=wG[1], g0z=wG[2];
        float g2x=wG[3], g2y=wG[4], g2z=wG[5];
        float g3x=wG[6], g3y=wG[7], g3z=wG[8];
        float d3 = g3x*e3x + g3y*e3y + g3z*e3z;
        float in3 = 1.0f/f_n3;
        float dcx = (g3x - d3*e3x)*in3;
        float dcy = (g3y - d3*e3y)*in3;
        float dcz = (g3z - d3*e3z)*in3;
        float gr0x = r1y*dcz - r1z*dcy;
        float gr0y = r1z*dcx - r1x*dcz;
        float gr0z = r1x*dcy - r1y*dcx;
        float gr1x = dcy*r0z - dcz*r0y;
        float gr1y = dcz*r0x - dcx*r0z;
        float gr1z = dcx*r0y - dcy*r0x;
        float d2 = g2x*e2x + g2y*e2y + g2z*e2z;
        float in2 = 1.0f/f_n2;
        float dvx = (g2x - d2*e2x)*in2;
        float dvy = (g2y - d2*e2y)*in2;
        float dvz = (g2z - d2*e2z)*in2;
        gr1x += dvx; gr1y += dvy; gr1z += dvz;
        gr0x -= f_s*dvx; gr0y -= f_s*dvy; gr0z -= f_s*dvz;
        float dss = -(dvx*r0x + dvy*r0y + dvz*r0z);
        gr0x += dss*r1x; gr0y += dss*r1y; gr0z += dss*r1z;
        gr1x += dss*r0x; gr1y += dss*r0y; gr1z += dss*r0z;
        gr0x += g0x; gr0y += g0y; gr0z += g0z;
        float de0 = f_ld0 + FEPS;
        float dot0 = gr0x*u0x + gr0y*u0y + gr0z*u0z;
        float k0 = dot0 / (f_ld0 * de0 * de0);
        float gu0x = gr0x/de0 - k0*u0x;
        float gu0y = gr0y/de0 - k0*u0y;
        float gu0z = gr0z/de0 - k0*u0z;
        float de1 = f_ld1 + FEPS;
        float dot1 = gr1x*u1x + gr1y*u1y + gr1z*u1z;
        float k1 = dot1 / (f_ld1 * de1 * de1);
        float gu1x = gr1x/de1 - k1*u1x;
        float gu1y = gr1y/de1 - k1*u1y;
        float gu1z = gr1z/de1 - k1*u1z;
        wgx[f_s0] += gu0x; wgy[f_s0] += gu0y; wgz[f_s0] += gu0z;
        wgx[f_s1] += gu1x; wgy[f_s1] += gu1y; wgz[f_s1] += gu1z;
        wgx[NNB] = wFi[0] - (gu0x + gu1x);
        wgy[NNB] = wFi[1] - (gu0y + gu1y);
        wgz[NNB] = wFi[2] - (gu0z + gu1z);
    }
    WSYNC();

    if (use_gather) {
        // ---- sort (j<<32|slot), write grec in j-order, build bitmap ----
        u64 e0, e1, e2, e3;
        {
            auto mk = [&](int s) -> u64 {
                if (s < NNB) {
                    int j = wsni[s];
                    return (j >= 0) ? ((((u64)(uint32_t)j) << 32) | (uint32_t)s) : ~0ull;
                }
                if (s == NNB) return (((u64)(uint32_t)i) << 32) | (uint32_t)NNB;
                return ~0ull;
            };
            e0 = mk(lane); e1 = mk(lane+64); e2 = mk(lane+128); e3 = mk(lane+192);
        }
        #pragma unroll 1
        for (int size = 2; size <= 256; size <<= 1) {
            #pragma unroll 1
            for (int stride = size >> 1; stride > 0; stride >>= 1) {
                if (stride == 128) {
                    cas_(e0, e2, true); cas_(e1, e3, true);
                } else if (stride == 64) {
                    cas_(e0, e1, ((lane & size) == 0));
                    cas_(e2, e3, (((lane + 128) & size) == 0));
                } else {
                    bool keep_lo = (lane & stride) == 0;
                    e0 = casx_(e0, stride, ((lane        & size) == 0), keep_lo);
                    e1 = casx_(e1, stride, (((lane +  64) & size) == 0), keep_lo);
                    e2 = casx_(e2, stride, (((lane + 128) & size) == 0), keep_lo);
                    e3 = casx_(e3, stride, (((lane + 192) & size) == 0), keep_lo);
                }
            }
        }
        #pragma unroll
        for (int p = 0; p < 4; ++p) {
            u64 e = (p == 0) ? e0 : (p == 1) ? e1 : (p == 2) ? e2 : e3;
            int r = lane + 64 * p;
            if (e != ~0ull) {
                int j = (int)(e >> 32);
                int slot = (int)(uint32_t)e;
                float* gv = grec + ((size_t)atom * NRECROW + r) * 3;
                gv[0] = wgx[slot]; gv[1] = wgy[slot]; gv[2] = wgz[slot];
                atomicOr(&wb[j >> 5], 1u << (j & 31));
            }
        }
        WSYNC();
        // prefix counts per u64 word + transposed stores
        int pc = 0;
        if (lane < 32) pc = __popc(wb[2*lane]) + __popc(wb[2*lane + 1]);
        int incl = pc;
        for (int o = 1; o < 32; o <<= 1) {
            int v = __shfl_up(incl, o, 64);
            if (lane >= o) incl += v;
        }
        if (lane < 32) {
            pcntT[(size_t)lane * BNtot + atom] = (u16)(incl - pc);
            bmT[(size_t)lane * BNtot + atom] = ((u64)wb[2*lane + 1] << 32) | wb[2*lane];
        }
    } else {
        // fallback: direct atomic scatter
        float* Fout = out + B;
        for (int s = lane; s <= NNB; s += WAVE) {
            int j = (s < NNB) ? wsni[s] : i;
            if (j >= 0 && (s < NNB ? true : true)) {
                float* Fj = Fout + 3*((size_t)bofs + j);
                atomicAdd(&Fj[0], wgx[s]);
                atomicAdd(&Fj[1], wgy[s]);
                atomicAdd(&Fj[2], wgz[s]);
            }
        }
    }

    if (lane == 0) atomicAdd(&out[b], esum);
}

__global__ __launch_bounds__(256)
void gather_kernel(const u64* __restrict__ bmT, const u16* __restrict__ pcntT,
                   const float* __restrict__ grec, float* __restrict__ out,
                   int B, int N)
{
    const int wv = threadIdx.x >> 6;
    const int lane = threadIdx.x & 63;
    const int t = blockIdx.x * WPB + wv;
    const int BNtot = B * N;
    if (t >= BNtot) return;
    const int b = t / N;
    const int j = t - b * N;

    const int w = j >> 6;
    const u64 bitm = 1ull << (j & 63);
    const u64 lowmask = bitm - 1ull;
    const u64* bmrow = bmT + (size_t)w * BNtot + (size_t)b * N;
    const u16* pcrow = pcntT + (size_t)w * BNtot + (size_t)b * N;

    float fx = 0, fy = 0, fz = 0;
    const int NIT = (N + WAVE - 1) / WAVE;
    for (int it = 0; it < NIT; ++it) {
        int i = it * WAVE + lane;
        if (i < N) {
            u64 word = bmrow[i];
            if (word & bitm) {
                int rank = (int)pcrow[i] + __popcll(word & lowmask);
                const float* gv = grec + ((size_t)(b*N + i) * NRECROW + rank) * 3;
                fx += gv[0]; fy += gv[1]; fz += gv[2];
            }
        }
    }
    for (int o = 1; o < 64; o <<= 1) {
        fx += __shfl_xor(fx, o, 64);
        fy += __shfl_xor(fy, o, 64);
        fz += __shfl_xor(fz, o, 64);
    }
    if (lane == 0) {
        float* F = out + B + 3*(size_t)t;
        F[0] = fx; F[1] = fy; F[2] = fz;
    }
}

extern "C" void kernel_launch(void* const* d_in, const int* in_sizes, int n_in,
                              void* d_out, int out_size, void* d_ws, size_t ws_size,
                              hipStream_t stream) {
    const float* xyz  = (const float*)d_in[0];
    const int*   types = (const int*)d_in[1];
    const void*  boxp = d_in[2];
    int BN = in_sizes[1];              // B*N
    int B = out_size - 3*BN;           // out = energy(B) + forces(3BN)
    if (B < 1) B = 1;
    int N = BN / B;

    // ws layout: X4 | W0Ta | W0Tb | W1Ta | W1Tb | grec | bmT | pcntT
    size_t off = 0;
    size_t x4Bytes   = (size_t)BN * 16;
    size_t w0tBytes  = (size_t)DDIM * HID * 4;
    size_t w1tBytes  = (size_t)HID * HID * 4;
    size_t grecBytes = (size_t)BN * NRECROW * 3 * 4;
    size_t bmBytes   = (size_t)32 * BN * 8;
    size_t pcBytes   = (size_t)32 * BN * 2;

    float4* X4 = (float4*)((char*)d_ws + off); off += x4Bytes;
    float* W0Ta = nullptr, *W0Tb = nullptr, *W1Ta = nullptr, *W1Tb = nullptr;
    int haveW = 0;
    if (ws_size >= off + 2*w0tBytes + 2*w1tBytes) {
        W0Ta = (float*)((char*)d_ws + off); off += w0tBytes;
        W0Tb = (float*)((char*)d_ws + off); off += w0tBytes;
        W1Ta = (float*)((char*)d_ws + off); off += w1tBytes;
        W1Tb = (float*)((char*)d_ws + off); off += w1tBytes;
        haveW = 1;
    }
    float* grec = nullptr; u64* bmT = nullptr; u16* pcntT = nullptr;
    int use_gather = 0;
    if (ws_size >= off + grecBytes + bmBytes + pcBytes) {
        grec  = (float*)((char*)d_ws + off); off += grecBytes;
        bmT   = (u64*)((char*)d_ws + off);   off += bmBytes;
        pcntT = (u16*)((char*)d_ws + off);   off += pcBytes;
        use_gather = 1;
    }

    // gather mode: forces fully overwritten by gather; only energies accumulate
    hipMemsetAsync(d_out, 0,
                   (use_gather ? (size_t)B : (size_t)out_size) * sizeof(float),
                   stream);

    int prepM = DDIM * HID > BN ? DDIM * HID : BN;
    prep_kernel<<<dim3((prepM + 255)/256), dim3(256), 0, stream>>>(
        xyz, types, X4, BN,
        (const float*)d_in[3], (const float*)d_in[9],
        (const float*)d_in[5], (const float*)d_in[11],
        W0Ta, W0Tb, W1Ta, W1Tb, haveW);

    int nbA = (BN + WPB - 1) / WPB;
    md_kernel<<<dim3(nbA), dim3(256), 0, stream>>>(
        X4, boxp,
        (const float*)d_in[3],  (const float*)d_in[4],
        (const float*)d_in[5],  (const float*)d_in[6],
        (const float*)d_in[7],  (const float*)d_in[8],
        (const float*)d_in[9],  (const float*)d_in[10],
        (const float*)d_in[11], (const float*)d_in[12],
        (const float*)d_in[13], (const float*)d_in[14],
        W0Ta, W0Tb, W1Ta, W1Tb,
        (float*)d_out, grec, bmT, pcntT, use_gather, B, N);

    if (use_gather) {
        gather_kernel<<<dim3(nbA), dim3(256), 0, stream>>>(
            bmT, pcntT, grec, (float*)d_out, B, N);
    }
}